// Round 8
// baseline (322.429 us; speedup 1.0000x reference)
//
#include <hip/hip_runtime.h>
#include <hip/hip_bf16.h>

typedef __attribute__((ext_vector_type(4)))  float f32x4;
typedef __attribute__((ext_vector_type(16))) float f32x16;
typedef __attribute__((ext_vector_type(8)))  short s16x8;
typedef __attribute__((ext_vector_type(8)))  unsigned short u16x8_t;
typedef __attribute__((ext_vector_type(4)))  int i32x4;

static __device__ __forceinline__ unsigned short f2b(float f) {
    __hip_bfloat16 h = __float2bfloat16(f);
    return __builtin_bit_cast(unsigned short, h);
}

// async global->LDS, 16 bytes per lane (dest must be linear: base + lane*16)
static __device__ __forceinline__ void gload_lds16(const unsigned short* g, unsigned short* l) {
    __builtin_amdgcn_global_load_lds(
        (const __attribute__((address_space(1))) void*)g,
        (__attribute__((address_space(3))) void*)l, 16, 0, 0);
}

// ---------------------------------------------------------------------------
// f32 -> bf16 vectorized x4
// ---------------------------------------------------------------------------
__global__ void cvt_f32_to_bf16(const float* __restrict__ src,
                                unsigned short* __restrict__ dst, int n4) {
    int i = blockIdx.x * blockDim.x + threadIdx.x;
    int stride = gridDim.x * blockDim.x;
    for (; i < n4; i += stride) {
        f32x4 v = reinterpret_cast<const f32x4*>(src)[i];
        ushort4 o;
        o.x = f2b(v.x); o.y = f2b(v.y); o.z = f2b(v.z); o.w = f2b(v.w);
        reinterpret_cast<ushort4*>(dst)[i] = o;
    }
}

// All 4 weight matrices -> one concatenated bf16 buffer [3072][768]
__global__ void cvt_weights(const float* __restrict__ wq, const float* __restrict__ wk,
                            const float* __restrict__ wv, const float* __restrict__ wo,
                            unsigned short* __restrict__ dst, int quarter4) {
    int i = blockIdx.x * blockDim.x + threadIdx.x;  // in float4 units
    int seg = i / quarter4;
    int j = i - seg * quarter4;
    const float* src = (seg == 0) ? wq : (seg == 1) ? wk : (seg == 2) ? wv : wo;
    f32x4 v = reinterpret_cast<const f32x4*>(src)[j];
    ushort4 o;
    o.x = f2b(v.x); o.y = f2b(v.y); o.z = f2b(v.z); o.w = f2b(v.w);
    reinterpret_cast<ushort4*>(dst)[i] = o;
}

// ---------------------------------------------------------------------------
// Merged NT GEMM (unchanged from R7: dbuf + global_load_lds + XCD swizzle).
// C[m][n] = A_seg[m][:] . Wcat[n][:], N = 3072 in 4 segments of 768:
// Q (bf16, *qscale w/ LOG2E folded) | K (bf16) | V (bf16, per-head transpose)
// | O (f32 adj). 128x128 tile, 4 waves, BK=64, 12 k-steps.
// ---------------------------------------------------------------------------
__global__ __launch_bounds__(256) void gemm_qkvo(
    const unsigned short* __restrict__ A1,
    const unsigned short* __restrict__ A2,
    const unsigned short* __restrict__ Wcat,
    const float* __restrict__ bq, const float* __restrict__ bk,
    const float* __restrict__ bv, const float* __restrict__ bo,
    unsigned short* __restrict__ Qb,
    unsigned short* __restrict__ Kb,
    unsigned short* __restrict__ Vtb,
    float* __restrict__ adj,
    float qscale)
{
    __shared__ unsigned short As[2][128 * 64];
    __shared__ unsigned short Bs[2][128 * 64];

    const int bid = blockIdx.x;
    const int wg = (bid & 7) * 192 + (bid >> 3);   // 1536%8==0 -> bijective
    const int mblk = wg / 24;
    const int nblk = wg - mblk * 24;
    const int n0g = nblk * 128;
    const int seg = nblk / 6;
    const int n0 = n0g - seg * 768;
    const int m0 = mblk * 128;
    const unsigned short* A = (seg == 1 || seg == 2) ? A2 : A1;
    const float* bias = (seg == 0) ? bq : (seg == 1) ? bk : (seg == 2) ? bv : bo;

    const int tid = threadIdx.x;
    const int w = tid >> 6, lane = tid & 63;
    const int lg = lane >> 4, lr = lane & 15;
    const int wm = w >> 1, wn = w & 1;
    const int srow = tid >> 3;
    const int scol = (tid & 7) * 8;

    const unsigned short* Ag = A    + (size_t)(m0  + srow) * 768 + scol;
    const unsigned short* Bg = Wcat + (size_t)(n0g + srow) * 768 + scol;

    auto STAGE = [&](int buf, int k0) {
#pragma unroll
        for (int c = 0; c < 4; c++) {
            gload_lds16(Ag + c * 32 * 768 + k0, &As[buf][tid * 8 + c * 2048]);
            gload_lds16(Bg + c * 32 * 768 + k0, &Bs[buf][tid * 8 + c * 2048]);
        }
    };

    f32x4 acc[4][4];
#pragma unroll
    for (int i = 0; i < 4; i++)
#pragma unroll
        for (int j = 0; j < 4; j++) acc[i][j] = f32x4{0.f, 0.f, 0.f, 0.f};

    STAGE(0, 0);
    __syncthreads();

#pragma unroll 1
    for (int t = 0; t < 12; t++) {
        const int curb = t & 1;
        if (t + 1 < 12) STAGE(curb ^ 1, (t + 1) * 64);
#pragma unroll
        for (int kk = 0; kk < 2; ++kk) {
            s16x8 af[4], bf[4];
#pragma unroll
            for (int mi = 0; mi < 4; mi++)
                af[mi] = *reinterpret_cast<const s16x8*>(&As[curb][(wm * 64 + mi * 16 + lr) * 64 + kk * 32 + lg * 8]);
#pragma unroll
            for (int ni = 0; ni < 4; ni++)
                bf[ni] = *reinterpret_cast<const s16x8*>(&Bs[curb][(wn * 64 + ni * 16 + lr) * 64 + kk * 32 + lg * 8]);
#pragma unroll
            for (int mi = 0; mi < 4; mi++)
#pragma unroll
                for (int ni = 0; ni < 4; ni++)
                    acc[mi][ni] = __builtin_amdgcn_mfma_f32_16x16x32_bf16(af[mi], bf[ni], acc[mi][ni], 0, 0, 0);
        }
        __syncthreads();
    }

#pragma unroll
    for (int ni = 0; ni < 4; ni++) {
        int n = n0 + wn * 64 + ni * 16 + lr;
        float bn = bias[n];
#pragma unroll
        for (int mi = 0; mi < 4; mi++) {
#pragma unroll
            for (int i = 0; i < 4; i++) {
                int m = m0 + wm * 64 + mi * 16 + 4 * lg + i;
                float v = acc[mi][ni][i] + bn;
                if (seg == 0) {
                    Qb[(size_t)m * 768 + n] = f2b(v * qscale);
                } else if (seg == 1) {
                    Kb[(size_t)m * 768 + n] = f2b(v);
                } else if (seg == 2) {
                    int bb = m >> 11, ss = m & 2047;
                    Vtb[((size_t)(bb * 768 + n) << 11) + ss] = f2b(v);
                } else {
                    adj[(size_t)m * 768 + n] = v;
                }
            }
        }
    }
}

// ---------------------------------------------------------------------------
// Flash attention v6 — k-split partials (flash-decoding style).
// Grid (48 bh, 16 qblk, 2 khalf). Block: 256 threads (4 waves), wave owns
// 32 q rows. Each block processes 1024 k (16 KT=64 tiles), writes
// UNNORMALIZED partial o = sum p*V and l = sum p  (exactly additive because
// there is no running max: logits bounded, softmax shift-invariant, LOG2E
// folded into Q prescale -> p = exp2(sc)).
// 36.8 KB LDS + <=128 VGPR -> 4 blocks/CU resident = 16 waves/CU.
// Swapped QK^T: S^T[k][q] = mfma(K, Q^T); C col = lane&31 = q,
//   row = (r&3)+8*(r>>2)+4*hi = k.  Swapped PV: out^T = mfma(V^T, P^T).
// P^T frags in-register via v_cvt_pk_bf16_f32 + v_permlane32_swap_b32.
// ---------------------------------------------------------------------------
__global__ __launch_bounds__(256, 4) void attn_partial(
    const unsigned short* __restrict__ Qb,
    const unsigned short* __restrict__ Kb,
    const unsigned short* __restrict__ Vt,
    float* __restrict__ po0,   // == d_out (half-0 partial)
    float* __restrict__ po1,   // overlays dead v1b/v2b
    float* __restrict__ lp0,   // overlays dead wcat
    float* __restrict__ lp1)
{
    __shared__ unsigned short Ksm[2][64][72];   // [buf][k][d]
    __shared__ unsigned short Vsm[2][64][72];   // [buf][d][k]

    const int bh = blockIdx.x;
    const int b = bh / 12, h = bh - 12 * (bh / 12);
    const int z = blockIdx.z;
    const int tb = z << 10;                     // k-range base (0 or 1024)
    float* __restrict__ po = z ? po1 : po0;
    float* __restrict__ lp = z ? lp1 : lp0;

    const int tid = threadIdx.x, w = tid >> 6, lane = tid & 63;
    const int ql = lane & 31, hi = lane >> 5;
    const int q0 = blockIdx.y * 128 + w * 32;

    const size_t qbase = ((size_t)(b * 2048 + q0 + ql)) * 768 + h * 64;
    s16x8 qreg[4];
#pragma unroll
    for (int ds = 0; ds < 4; ds++)
        qreg[ds] = *reinterpret_cast<const s16x8*>(Qb + qbase + ds * 16 + hi * 8);

    f32x16 z16;
#pragma unroll
    for (int r = 0; r < 16; r++) z16[r] = 0.f;
    f32x16 acc[2];
#pragma unroll
    for (int dd = 0; dd < 2; dd++) acc[dd] = z16;
    float l = 0.f;

    const size_t kbase = (size_t)b * 2048 * 768 + (size_t)h * 64;
    const size_t vbase = (size_t)(b * 768 + h * 64) * 2048;

    const int krow = tid >> 3, kc8 = (tid & 7) * 8;

    u16x8_t kst[2], vst[2];
    auto load_tile = [&](int t0) {
#pragma unroll
        for (int i = 0; i < 2; i++)
            kst[i] = *reinterpret_cast<const u16x8_t*>(Kb + kbase + (size_t)(t0 + i * 32 + krow) * 768 + kc8);
#pragma unroll
        for (int i = 0; i < 2; i++)
            vst[i] = *reinterpret_cast<const u16x8_t*>(Vt + vbase + (size_t)(i * 32 + krow) * 2048 + t0 + kc8);
    };
    auto write_tile = [&](int buf) {
#pragma unroll
        for (int i = 0; i < 2; i++)
            *reinterpret_cast<u16x8_t*>(&Ksm[buf][i * 32 + krow][kc8]) = kst[i];
#pragma unroll
        for (int i = 0; i < 2; i++)
            *reinterpret_cast<u16x8_t*>(&Vsm[buf][i * 32 + krow][kc8]) = vst[i];
    };

    load_tile(tb);
    write_tile(0);
    load_tile(tb + 64);
    __syncthreads();

#pragma unroll 1
    for (int t = 0; t < 16; t++) {
        const int cur = t & 1;
        if (t + 1 < 16) write_tile(cur ^ 1);            // tile t+1 regs -> other buffer
        if (t + 2 < 16) load_tile(tb + (t + 2) * 64);   // issue next-next tile loads

#pragma unroll
        for (int kb2 = 0; kb2 < 2; kb2++) {
            // --- QK^T for this 32k slab ---
            s16x8 ka0 = *reinterpret_cast<const s16x8*>(&Ksm[cur][kb2 * 32 + ql][0 * 16 + hi * 8]);
            s16x8 ka1 = *reinterpret_cast<const s16x8*>(&Ksm[cur][kb2 * 32 + ql][1 * 16 + hi * 8]);
            s16x8 ka2 = *reinterpret_cast<const s16x8*>(&Ksm[cur][kb2 * 32 + ql][2 * 16 + hi * 8]);
            s16x8 ka3 = *reinterpret_cast<const s16x8*>(&Ksm[cur][kb2 * 32 + ql][3 * 16 + hi * 8]);
            __builtin_amdgcn_s_setprio(1);
            f32x16 sc = __builtin_amdgcn_mfma_f32_32x32x16_bf16(ka0, qreg[0], z16, 0, 0, 0);
            sc = __builtin_amdgcn_mfma_f32_32x32x16_bf16(ka1, qreg[1], sc, 0, 0, 0);
            sc = __builtin_amdgcn_mfma_f32_32x32x16_bf16(ka2, qreg[2], sc, 0, 0, 0);
            sc = __builtin_amdgcn_mfma_f32_32x32x16_bf16(ka3, qreg[3], sc, 0, 0, 0);
            __builtin_amdgcn_s_setprio(0);

            // --- p = exp2(sc), tree-sum ---
            float p[16];
#pragma unroll
            for (int r = 0; r < 16; r++) p[r] = __builtin_exp2f(sc[r]);
            {
                float s0 = p[0] + p[1],  s1 = p[2] + p[3],  s2 = p[4] + p[5],  s3 = p[6] + p[7];
                float s4 = p[8] + p[9],  s5 = p[10] + p[11], s6 = p[12] + p[13], s7 = p[14] + p[15];
                float t0a = s0 + s1, t1a = s2 + s3, t2a = s4 + s5, t3a = s6 + s7;
                l += (t0a + t1a) + (t2a + t3a);
            }

            // --- pack P^T fragments in-register ---
            s16x8 pf[2];
            {
                unsigned int a0, b0, a1, b1, a2, b2, a3, b3;
                asm("v_cvt_pk_bf16_f32 %0, %1, %2" : "=v"(a0) : "v"(p[0]),  "v"(p[1]));
                asm("v_cvt_pk_bf16_f32 %0, %1, %2" : "=v"(b0) : "v"(p[4]),  "v"(p[5]));
                asm("v_cvt_pk_bf16_f32 %0, %1, %2" : "=v"(a1) : "v"(p[2]),  "v"(p[3]));
                asm("v_cvt_pk_bf16_f32 %0, %1, %2" : "=v"(b1) : "v"(p[6]),  "v"(p[7]));
                asm("v_cvt_pk_bf16_f32 %0, %1, %2" : "=v"(a2) : "v"(p[8]),  "v"(p[9]));
                asm("v_cvt_pk_bf16_f32 %0, %1, %2" : "=v"(b2) : "v"(p[12]), "v"(p[13]));
                asm("v_cvt_pk_bf16_f32 %0, %1, %2" : "=v"(a3) : "v"(p[10]), "v"(p[11]));
                asm("v_cvt_pk_bf16_f32 %0, %1, %2" : "=v"(b3) : "v"(p[14]), "v"(p[15]));
                asm volatile("v_permlane32_swap_b32 %0, %1" : "+v"(a0), "+v"(b0));
                asm volatile("v_permlane32_swap_b32 %0, %1" : "+v"(a1), "+v"(b1));
                asm volatile("v_permlane32_swap_b32 %0, %1" : "+v"(a2), "+v"(b2));
                asm volatile("v_permlane32_swap_b32 %0, %1" : "+v"(a3), "+v"(b3));
                i32x4 w0; w0[0] = (int)a0; w0[1] = (int)a1; w0[2] = (int)b0; w0[3] = (int)b1;
                i32x4 w1; w1[0] = (int)a2; w1[1] = (int)a3; w1[2] = (int)b2; w1[3] = (int)b3;
                pf[0] = __builtin_bit_cast(s16x8, w0);
                pf[1] = __builtin_bit_cast(s16x8, w1);
            }

            // --- PV: out^T += V^T . P^T ---
            s16x8 va00 = *reinterpret_cast<const s16x8*>(&Vsm[cur][0 * 32 + ql][kb2 * 32 + 0 * 16 + hi * 8]);
            s16x8 va01 = *reinterpret_cast<const s16x8*>(&Vsm[cur][1 * 32 + ql][kb2 * 32 + 0 * 16 + hi * 8]);
            s16x8 va10 = *reinterpret_cast<const s16x8*>(&Vsm[cur][0 * 32 + ql][kb2 * 32 + 1 * 16 + hi * 8]);
            s16x8 va11 = *reinterpret_cast<const s16x8*>(&Vsm[cur][1 * 32 + ql][kb2 * 32 + 1 * 16 + hi * 8]);
            __builtin_amdgcn_s_setprio(1);
            acc[0] = __builtin_amdgcn_mfma_f32_32x32x16_bf16(va00, pf[0], acc[0], 0, 0, 0);
            acc[1] = __builtin_amdgcn_mfma_f32_32x32x16_bf16(va01, pf[0], acc[1], 0, 0, 0);
            acc[0] = __builtin_amdgcn_mfma_f32_32x32x16_bf16(va10, pf[1], acc[0], 0, 0, 0);
            acc[1] = __builtin_amdgcn_mfma_f32_32x32x16_bf16(va11, pf[1], acc[1], 0, 0, 0);
            __builtin_amdgcn_s_setprio(0);
        }
        __syncthreads();
    }

    l += __shfl_xor(l, 32, 64);   // combine hi halves (duplicated q state)

    // write unnormalized partial o (f32) and partial l
#pragma unroll
    for (int dd = 0; dd < 2; dd++) {
#pragma unroll
        for (int rg = 0; rg < 4; rg++) {
            int d0 = dd * 32 + rg * 8 + hi * 4;
            f32x4 o;
#pragma unroll
            for (int i = 0; i < 4; i++) o[i] = acc[dd][rg * 4 + i];
            *reinterpret_cast<f32x4*>(po + qbase + d0) = o;
        }
    }
    if (lane < 32) lp[(b * 2048 + q0 + ql) * 12 + h] = l;
}

// ---------------------------------------------------------------------------
// Combine: out = alpha*(po0+po1)/(l0+l1) + beta*adj.  po0 aliases out
// (same-thread 1:1 read-then-write, safe). i indexes f32x4 units.
// ---------------------------------------------------------------------------
__global__ __launch_bounds__(256) void combine_out(
    const float* __restrict__ po1,
    const float* __restrict__ lp0, const float* __restrict__ lp1,
    const float* __restrict__ adj,
    const float* __restrict__ alpha_p, const float* __restrict__ beta_p,
    float* __restrict__ out)
{
    int i = blockIdx.x * 256 + threadIdx.x;   // 1,572,864 f32x4 units
    int q = i / 192;
    int c = i - q * 192;
    int h = c >> 4;
    float l = lp0[q * 12 + h] + lp1[q * 12 + h];
    const float s = (*alpha_p) / l;
    const float beta = *beta_p;
    f32x4 a = reinterpret_cast<const f32x4*>(out)[i];
    f32x4 bq = reinterpret_cast<const f32x4*>(po1)[i];
    f32x4 ad = reinterpret_cast<const f32x4*>(adj)[i];
    f32x4 o;
#pragma unroll
    for (int j = 0; j < 4; j++) o[j] = (a[j] + bq[j]) * s + beta * ad[j];
    reinterpret_cast<f32x4*>(out)[i] = o;
}

// ---------------------------------------------------------------------------
extern "C" void kernel_launch(void* const* d_in, const int* in_sizes, int n_in,
                              void* d_out, int out_size, void* d_ws, size_t ws_size,
                              hipStream_t stream) {
    const float* v1 = (const float*)d_in[0];
    const float* v2 = (const float*)d_in[1];
    const float* Wq = (const float*)d_in[2];
    const float* bq = (const float*)d_in[3];
    const float* Wk = (const float*)d_in[4];
    const float* bk = (const float*)d_in[5];
    const float* Wv = (const float*)d_in[6];
    const float* bv = (const float*)d_in[7];
    const float* Wo = (const float*)d_in[8];
    const float* bo = (const float*)d_in[9];
    const float* alpha = (const float*)d_in[10];
    const float* beta = (const float*)d_in[11];
    float* out = (float*)d_out;

    const size_t ACT = (size_t)8192 * 768;
    const size_t WSZ = (size_t)768 * 768;
    char* ws = (char*)d_ws;
    size_t off = 0;
    auto alloc = [&](size_t bytes) {
        char* p = ws + off;
        off += (bytes + 255) & ~(size_t)255;
        return p;
    };
    unsigned short* v1b  = (unsigned short*)alloc(ACT * 2);
    unsigned short* v2b  = (unsigned short*)alloc(ACT * 2);
    unsigned short* wcat = (unsigned short*)alloc(4 * WSZ * 2);
    unsigned short* Qb   = (unsigned short*)alloc(ACT * 2);
    unsigned short* Kb   = (unsigned short*)alloc(ACT * 2);
    unsigned short* Vtb  = (unsigned short*)alloc(ACT * 2);
    float* adj = (float*)alloc(ACT * 4);

    // Overlays (regions dead after gemm_qkvo):
    float* po1 = (float*)v1b;        // 25.2 MB partial (v1b+v2b = exactly ACT*4 bytes)
    float* lp0 = (float*)wcat;       // 786 KB of the 4.7 MB wcat region
    float* lp1 = lp0 + 8192 * 12;
    float* po0 = out;                // d_out doubles as half-0 partial

    cvt_f32_to_bf16<<<dim3(1024), dim3(256), 0, stream>>>(v1, v1b, (int)(ACT / 4));
    cvt_f32_to_bf16<<<dim3(1024), dim3(256), 0, stream>>>(v2, v2b, (int)(ACT / 4));
    cvt_weights<<<dim3((int)(4 * WSZ / 4 / 256)), dim3(256), 0, stream>>>(
        Wq, Wk, Wv, Wo, wcat, (int)(WSZ / 4));

    // 1/sqrt(768) * log2(e): folds softmax's base-2 conversion into Q.
    const float qscale = 0.03608439182435161f * 1.4426950408889634f;
    gemm_qkvo<<<dim3(1536), dim3(256), 0, stream>>>(
        v1b, v2b, wcat, bq, bk, bv, bo, Qb, Kb, Vtb, adj, qscale);

    attn_partial<<<dim3(48, 16, 2), dim3(256), 0, stream>>>(
        Qb, Kb, Vtb, po0, po1, lp0, lp1);

    combine_out<<<dim3(6144), dim3(256), 0, stream>>>(
        po1, lp0, lp1, adj, alpha, beta, out);
}

// Round 9
// 280.543 us; speedup vs baseline: 1.1493x; 1.1493x over previous
//
#include <hip/hip_runtime.h>
#include <hip/hip_bf16.h>

typedef __attribute__((ext_vector_type(4)))  float f32x4;
typedef __attribute__((ext_vector_type(16))) float f32x16;
typedef __attribute__((ext_vector_type(8)))  short s16x8;
typedef __attribute__((ext_vector_type(8)))  unsigned short u16x8_t;
typedef __attribute__((ext_vector_type(4)))  int i32x4;

static __device__ __forceinline__ unsigned short f2b(float f) {
    __hip_bfloat16 h = __float2bfloat16(f);
    return __builtin_bit_cast(unsigned short, h);
}

// async global->LDS, 16 bytes per lane (dest must be linear: base + lane*16)
static __device__ __forceinline__ void gload_lds16(const unsigned short* g, unsigned short* l) {
    __builtin_amdgcn_global_load_lds(
        (const __attribute__((address_space(1))) void*)g,
        (__attribute__((address_space(3))) void*)l, 16, 0, 0);
}

// ---------------------------------------------------------------------------
// f32 -> bf16 vectorized x4
// ---------------------------------------------------------------------------
__global__ void cvt_f32_to_bf16(const float* __restrict__ src,
                                unsigned short* __restrict__ dst, int n4) {
    int i = blockIdx.x * blockDim.x + threadIdx.x;
    int stride = gridDim.x * blockDim.x;
    for (; i < n4; i += stride) {
        f32x4 v = reinterpret_cast<const f32x4*>(src)[i];
        ushort4 o;
        o.x = f2b(v.x); o.y = f2b(v.y); o.z = f2b(v.z); o.w = f2b(v.w);
        reinterpret_cast<ushort4*>(dst)[i] = o;
    }
}

// All 4 weight matrices -> one concatenated bf16 buffer [3072][768]
__global__ void cvt_weights(const float* __restrict__ wq, const float* __restrict__ wk,
                            const float* __restrict__ wv, const float* __restrict__ wo,
                            unsigned short* __restrict__ dst, int quarter4) {
    int i = blockIdx.x * blockDim.x + threadIdx.x;  // in float4 units
    int seg = i / quarter4;
    int j = i - seg * quarter4;
    const float* src = (seg == 0) ? wq : (seg == 1) ? wk : (seg == 2) ? wv : wo;
    f32x4 v = reinterpret_cast<const f32x4*>(src)[j];
    ushort4 o;
    o.x = f2b(v.x); o.y = f2b(v.y); o.z = f2b(v.z); o.w = f2b(v.w);
    reinterpret_cast<ushort4*>(dst)[i] = o;
}

// ---------------------------------------------------------------------------
// Merged NT GEMM v3: counted-vmcnt pipeline (T3/T4-lite).
// BK=32, 4 LDS buffers (64 KB), 3-stage lookahead, raw s_barrier + counted
// s_waitcnt vmcnt(8) -- prefetch loads stay in flight ACROSS barriers
// (never drained to 0 in the main loop). sched_barrier(0) fences ds_reads
// from hoisting above the waitcnt (guide rule #18).
// C[m][n] = A_seg[m][:] . Wcat[n][:], N = 3072 in 4 segments of 768:
// Q (bf16, *qscale w/ LOG2E folded) | K (bf16) | V (bf16, per-head transpose)
// | O (f32 adj). 128x128 tile, 4 waves, 24 k-steps. XCD-chunked swizzle.
// ---------------------------------------------------------------------------
__global__ __launch_bounds__(256) void gemm_qkvo(
    const unsigned short* __restrict__ A1,
    const unsigned short* __restrict__ A2,
    const unsigned short* __restrict__ Wcat,
    const float* __restrict__ bq, const float* __restrict__ bk,
    const float* __restrict__ bv, const float* __restrict__ bo,
    unsigned short* __restrict__ Qb,
    unsigned short* __restrict__ Kb,
    unsigned short* __restrict__ Vtb,
    float* __restrict__ adj,
    float qscale)
{
    __shared__ unsigned short As[4 * 128 * 32];   // 32 KB (4 bufs x 8 KB)
    __shared__ unsigned short Bs[4 * 128 * 32];   // 32 KB

    const int bid = blockIdx.x;
    const int wg = (bid & 7) * 192 + (bid >> 3);   // 1536%8==0 -> bijective
    const int mblk = wg / 24;
    const int nblk = wg - mblk * 24;
    const int n0g = nblk * 128;
    const int seg = nblk / 6;
    const int n0 = n0g - seg * 768;
    const int m0 = mblk * 128;
    const unsigned short* A = (seg == 1 || seg == 2) ? A2 : A1;
    const float* bias = (seg == 0) ? bq : (seg == 1) ? bk : (seg == 2) ? bv : bo;

    const int tid = threadIdx.x;
    const int w = tid >> 6, lane = tid & 63;
    const int lg = lane >> 4, lr = lane & 15;
    const int wm = w >> 1, wn = w & 1;
    const int srow = tid >> 2;          // 0..63 (staging row, BK=32: 64 B/row)
    const int scol = (tid & 3) * 8;     // elem

    const unsigned short* Ag = A    + (size_t)(m0  + srow) * 768 + scol;
    const unsigned short* Bg = Wcat + (size_t)(n0g + srow) * 768 + scol;

    // 4 gload_lds per STAGE (2 A + 2 B); dest byte tid*16 + c*4096 -> row
    // tid/4 + c*64, matching the source row: linear-dest requirement holds.
    auto STAGE = [&](int buf, int k0) {
#pragma unroll
        for (int c = 0; c < 2; c++) {
            gload_lds16(Ag + (size_t)c * 64 * 768 + k0, &As[buf * 4096 + tid * 8 + c * 2048]);
            gload_lds16(Bg + (size_t)c * 64 * 768 + k0, &Bs[buf * 4096 + tid * 8 + c * 2048]);
        }
    };

    f32x4 acc[4][4];
#pragma unroll
    for (int i = 0; i < 4; i++)
#pragma unroll
        for (int j = 0; j < 4; j++) acc[i][j] = f32x4{0.f, 0.f, 0.f, 0.f};

    auto COMPUTE = [&](int buf) {
        s16x8 af[4], bf[4];
#pragma unroll
        for (int mi = 0; mi < 4; mi++)
            af[mi] = *reinterpret_cast<const s16x8*>(&As[buf * 4096 + (wm * 64 + mi * 16 + lr) * 32 + lg * 8]);
#pragma unroll
        for (int ni = 0; ni < 4; ni++)
            bf[ni] = *reinterpret_cast<const s16x8*>(&Bs[buf * 4096 + (wn * 64 + ni * 16 + lr) * 32 + lg * 8]);
#pragma unroll
        for (int mi = 0; mi < 4; mi++)
#pragma unroll
            for (int ni = 0; ni < 4; ni++)
                acc[mi][ni] = __builtin_amdgcn_mfma_f32_16x16x32_bf16(af[mi], bf[ni], acc[mi][ni], 0, 0, 0);
    };

    STAGE(0, 0);
    STAGE(1, 32);
    STAGE(2, 64);

#pragma unroll 1
    for (int t = 0; t < 22; t++) {
        // my stage-t loads done (t+1,t+2 = 8 remain in flight), THEN barrier
        // => everyone's stage-t done => safe to read buf t; buf (t-1) free.
        asm volatile("s_waitcnt vmcnt(8)" ::: "memory");
        __builtin_amdgcn_sched_barrier(0);
        __builtin_amdgcn_s_barrier();
        if (t + 3 < 24) STAGE((t + 3) & 3, (t + 3) * 32);
        COMPUTE(t & 3);
    }
    // t=22: stages 22,23 outstanding (8) -> need 22 done -> vmcnt(4)
    asm volatile("s_waitcnt vmcnt(4)" ::: "memory");
    __builtin_amdgcn_sched_barrier(0);
    __builtin_amdgcn_s_barrier();
    COMPUTE(22 & 3);
    // t=23: drain
    asm volatile("s_waitcnt vmcnt(0)" ::: "memory");
    __builtin_amdgcn_sched_barrier(0);
    __builtin_amdgcn_s_barrier();
    COMPUTE(23 & 3);

#pragma unroll
    for (int ni = 0; ni < 4; ni++) {
        int n = n0 + wn * 64 + ni * 16 + lr;
        float bn = bias[n];
#pragma unroll
        for (int mi = 0; mi < 4; mi++) {
#pragma unroll
            for (int i = 0; i < 4; i++) {
                int m = m0 + wm * 64 + mi * 16 + 4 * lg + i;
                float v = acc[mi][ni][i] + bn;
                if (seg == 0) {
                    Qb[(size_t)m * 768 + n] = f2b(v * qscale);
                } else if (seg == 1) {
                    Kb[(size_t)m * 768 + n] = f2b(v);
                } else if (seg == 2) {
                    int bb = m >> 11, ss = m & 2047;
                    Vtb[((size_t)(bb * 768 + n) << 11) + ss] = f2b(v);
                } else {
                    adj[(size_t)m * 768 + n] = v;
                }
            }
        }
    }
}

// ---------------------------------------------------------------------------
// Fused flash attention v7 = R6's best-measured v4 geometry + MFMA-computed l.
// Block: 256 threads (4 waves), wave owns 32 q rows; q-tile 128/block.
// Grid: (48 bh, 16 qblk). KT=64 k-tile, double-buffered LDS, 1 barrier/tile.
// No running max (logits bounded; softmax shift-invariant); LOG2E folded
// into Q prescale -> p = exp2(sc). l computed ON THE MATRIX PIPE via an
// all-ones A-fragment: l[q] = sum_k 1 * P^T[k][q] (replaces the 16-add VALU
// tree AND the final shfl -- the MFMA k-sum already crosses both hi halves).
// Swapped QK^T: S^T[k][q] = mfma(K, Q^T); C col = lane&31 = q,
//   row = (r&3)+8*(r>>2)+4*hi = k.  Swapped PV: out^T = mfma(V^T, P^T).
// P^T frags in-register via v_cvt_pk_bf16_f32 + v_permlane32_swap_b32.
// ---------------------------------------------------------------------------
__global__ __launch_bounds__(256, 3) void attn_fused(
    const unsigned short* __restrict__ Qb,
    const unsigned short* __restrict__ Kb,
    const unsigned short* __restrict__ Vt,
    const float* __restrict__ adj,
    const float* __restrict__ alpha_p,
    const float* __restrict__ beta_p,
    float* __restrict__ out)
{
    __shared__ unsigned short Ksm[2][64][72];   // [buf][k][d]
    __shared__ unsigned short Vsm[2][64][72];   // [buf][d][k]

    const int bh = blockIdx.x;
    const int b = bh / 12, h = bh - 12 * (bh / 12);
    const int tid = threadIdx.x, w = tid >> 6, lane = tid & 63;
    const int ql = lane & 31, hi = lane >> 5;
    const int q0 = blockIdx.y * 128 + w * 32;

    const size_t qbase = ((size_t)(b * 2048 + q0 + ql)) * 768 + h * 64;
    s16x8 qreg[4];
#pragma unroll
    for (int ds = 0; ds < 4; ds++)
        qreg[ds] = *reinterpret_cast<const s16x8*>(Qb + qbase + ds * 16 + hi * 8);

    s16x8 ones;
#pragma unroll
    for (int j = 0; j < 8; j++) ones[j] = (short)0x3F80;   // bf16 1.0

    f32x16 z16;
#pragma unroll
    for (int r = 0; r < 16; r++) z16[r] = 0.f;
    f32x16 acc[2];
#pragma unroll
    for (int dd = 0; dd < 2; dd++) acc[dd] = z16;
    f32x16 acc_l = z16;

    const size_t kbase = (size_t)b * 2048 * 768 + (size_t)h * 64;
    const size_t vbase = (size_t)(b * 768 + h * 64) * 2048;

    const int krow = tid >> 3, kc8 = (tid & 7) * 8;

    u16x8_t kst[2], vst[2];
    auto load_tile = [&](int t0) {
#pragma unroll
        for (int i = 0; i < 2; i++)
            kst[i] = *reinterpret_cast<const u16x8_t*>(Kb + kbase + (size_t)(t0 + i * 32 + krow) * 768 + kc8);
#pragma unroll
        for (int i = 0; i < 2; i++)
            vst[i] = *reinterpret_cast<const u16x8_t*>(Vt + vbase + (size_t)(i * 32 + krow) * 2048 + t0 + kc8);
    };
    auto write_tile = [&](int buf) {
#pragma unroll
        for (int i = 0; i < 2; i++)
            *reinterpret_cast<u16x8_t*>(&Ksm[buf][i * 32 + krow][kc8]) = kst[i];
#pragma unroll
        for (int i = 0; i < 2; i++)
            *reinterpret_cast<u16x8_t*>(&Vsm[buf][i * 32 + krow][kc8]) = vst[i];
    };

    load_tile(0);
    write_tile(0);
    load_tile(64);
    __syncthreads();

#pragma unroll 1
    for (int t = 0; t < 32; t++) {
        const int cur = t & 1;
        if (t + 1 < 32) write_tile(cur ^ 1);            // tile t+1 regs -> other buffer
        if (t + 2 < 32) load_tile((t + 2) * 64);        // issue next-next tile loads

#pragma unroll
        for (int kb2 = 0; kb2 < 2; kb2++) {
            // --- QK^T for this 32k slab ---
            s16x8 ka0 = *reinterpret_cast<const s16x8*>(&Ksm[cur][kb2 * 32 + ql][0 * 16 + hi * 8]);
            s16x8 ka1 = *reinterpret_cast<const s16x8*>(&Ksm[cur][kb2 * 32 + ql][1 * 16 + hi * 8]);
            s16x8 ka2 = *reinterpret_cast<const s16x8*>(&Ksm[cur][kb2 * 32 + ql][2 * 16 + hi * 8]);
            s16x8 ka3 = *reinterpret_cast<const s16x8*>(&Ksm[cur][kb2 * 32 + ql][3 * 16 + hi * 8]);
            __builtin_amdgcn_s_setprio(1);
            f32x16 sc = __builtin_amdgcn_mfma_f32_32x32x16_bf16(ka0, qreg[0], z16, 0, 0, 0);
            sc = __builtin_amdgcn_mfma_f32_32x32x16_bf16(ka1, qreg[1], sc, 0, 0, 0);
            sc = __builtin_amdgcn_mfma_f32_32x32x16_bf16(ka2, qreg[2], sc, 0, 0, 0);
            sc = __builtin_amdgcn_mfma_f32_32x32x16_bf16(ka3, qreg[3], sc, 0, 0, 0);
            __builtin_amdgcn_s_setprio(0);

            // --- p = exp2(sc) (LOG2E pre-folded into Q) ---
            float p[16];
#pragma unroll
            for (int r = 0; r < 16; r++) p[r] = __builtin_exp2f(sc[r]);

            // --- pack P^T fragments in-register ---
            s16x8 pf[2];
            {
                unsigned int a0, b0, a1, b1, a2, b2, a3, b3;
                asm("v_cvt_pk_bf16_f32 %0, %1, %2" : "=v"(a0) : "v"(p[0]),  "v"(p[1]));
                asm("v_cvt_pk_bf16_f32 %0, %1, %2" : "=v"(b0) : "v"(p[4]),  "v"(p[5]));
                asm("v_cvt_pk_bf16_f32 %0, %1, %2" : "=v"(a1) : "v"(p[2]),  "v"(p[3]));
                asm("v_cvt_pk_bf16_f32 %0, %1, %2" : "=v"(b1) : "v"(p[6]),  "v"(p[7]));
                asm("v_cvt_pk_bf16_f32 %0, %1, %2" : "=v"(a2) : "v"(p[8]),  "v"(p[9]));
                asm("v_cvt_pk_bf16_f32 %0, %1, %2" : "=v"(b2) : "v"(p[12]), "v"(p[13]));
                asm("v_cvt_pk_bf16_f32 %0, %1, %2" : "=v"(a3) : "v"(p[10]), "v"(p[11]));
                asm("v_cvt_pk_bf16_f32 %0, %1, %2" : "=v"(b3) : "v"(p[14]), "v"(p[15]));
                asm volatile("v_permlane32_swap_b32 %0, %1" : "+v"(a0), "+v"(b0));
                asm volatile("v_permlane32_swap_b32 %0, %1" : "+v"(a1), "+v"(b1));
                asm volatile("v_permlane32_swap_b32 %0, %1" : "+v"(a2), "+v"(b2));
                asm volatile("v_permlane32_swap_b32 %0, %1" : "+v"(a3), "+v"(b3));
                i32x4 w0; w0[0] = (int)a0; w0[1] = (int)a1; w0[2] = (int)b0; w0[3] = (int)b1;
                i32x4 w1; w1[0] = (int)a2; w1[1] = (int)a3; w1[2] = (int)b2; w1[3] = (int)b3;
                pf[0] = __builtin_bit_cast(s16x8, w0);
                pf[1] = __builtin_bit_cast(s16x8, w1);
            }

            // --- PV: out^T += V^T . P^T ; l += ones . P^T (matrix pipe) ---
            s16x8 va00 = *reinterpret_cast<const s16x8*>(&Vsm[cur][0 * 32 + ql][kb2 * 32 + 0 * 16 + hi * 8]);
            s16x8 va01 = *reinterpret_cast<const s16x8*>(&Vsm[cur][1 * 32 + ql][kb2 * 32 + 0 * 16 + hi * 8]);
            s16x8 va10 = *reinterpret_cast<const s16x8*>(&Vsm[cur][0 * 32 + ql][kb2 * 32 + 1 * 16 + hi * 8]);
            s16x8 va11 = *reinterpret_cast<const s16x8*>(&Vsm[cur][1 * 32 + ql][kb2 * 32 + 1 * 16 + hi * 8]);
            __builtin_amdgcn_s_setprio(1);
            acc[0] = __builtin_amdgcn_mfma_f32_32x32x16_bf16(va00, pf[0], acc[0], 0, 0, 0);
            acc[1] = __builtin_amdgcn_mfma_f32_32x32x16_bf16(va01, pf[0], acc[1], 0, 0, 0);
            acc_l  = __builtin_amdgcn_mfma_f32_32x32x16_bf16(ones, pf[0], acc_l, 0, 0, 0);
            acc[0] = __builtin_amdgcn_mfma_f32_32x32x16_bf16(va10, pf[1], acc[0], 0, 0, 0);
            acc[1] = __builtin_amdgcn_mfma_f32_32x32x16_bf16(va11, pf[1], acc[1], 0, 0, 0);
            acc_l  = __builtin_amdgcn_mfma_f32_32x32x16_bf16(ones, pf[1], acc_l, 0, 0, 0);
            __builtin_amdgcn_s_setprio(0);
        }
        __syncthreads();
    }

    const float l = acc_l[0];   // every output row of ones.P^T equals l[q]
    const float alpha = *alpha_p, beta = *beta_p;
    const float s = alpha / l;
#pragma unroll
    for (int dd = 0; dd < 2; dd++) {
#pragma unroll
        for (int rg = 0; rg < 4; rg++) {
            int d0 = dd * 32 + rg * 8 + hi * 4;
            size_t idx = qbase + d0;
            f32x4 av = *reinterpret_cast<const f32x4*>(adj + idx);
            f32x4 o;
#pragma unroll
            for (int i = 0; i < 4; i++)
                o[i] = acc[dd][rg * 4 + i] * s + beta * av[i];
            *reinterpret_cast<f32x4*>(out + idx) = o;
        }
    }
}

// ---------------------------------------------------------------------------
extern "C" void kernel_launch(void* const* d_in, const int* in_sizes, int n_in,
                              void* d_out, int out_size, void* d_ws, size_t ws_size,
                              hipStream_t stream) {
    const float* v1 = (const float*)d_in[0];
    const float* v2 = (const float*)d_in[1];
    const float* Wq = (const float*)d_in[2];
    const float* bq = (const float*)d_in[3];
    const float* Wk = (const float*)d_in[4];
    const float* bk = (const float*)d_in[5];
    const float* Wv = (const float*)d_in[6];
    const float* bv = (const float*)d_in[7];
    const float* Wo = (const float*)d_in[8];
    const float* bo = (const float*)d_in[9];
    const float* alpha = (const float*)d_in[10];
    const float* beta = (const float*)d_in[11];
    float* out = (float*)d_out;

    const size_t ACT = (size_t)8192 * 768;
    const size_t WSZ = (size_t)768 * 768;
    char* ws = (char*)d_ws;
    size_t off = 0;
    auto alloc = [&](size_t bytes) {
        char* p = ws + off;
        off += (bytes + 255) & ~(size_t)255;
        return p;
    };
    unsigned short* v1b  = (unsigned short*)alloc(ACT * 2);
    unsigned short* v2b  = (unsigned short*)alloc(ACT * 2);
    unsigned short* wcat = (unsigned short*)alloc(4 * WSZ * 2);
    unsigned short* Qb   = (unsigned short*)alloc(ACT * 2);
    unsigned short* Kb   = (unsigned short*)alloc(ACT * 2);
    unsigned short* Vtb  = (unsigned short*)alloc(ACT * 2);
    float* adj = (float*)alloc(ACT * 4);

    cvt_f32_to_bf16<<<dim3(1024), dim3(256), 0, stream>>>(v1, v1b, (int)(ACT / 4));
    cvt_f32_to_bf16<<<dim3(1024), dim3(256), 0, stream>>>(v2, v2b, (int)(ACT / 4));
    cvt_weights<<<dim3((int)(4 * WSZ / 4 / 256)), dim3(256), 0, stream>>>(
        Wq, Wk, Wv, Wo, wcat, (int)(WSZ / 4));

    // 1/sqrt(768) * log2(e): folds softmax's base-2 conversion into Q.
    const float qscale = 0.03608439182435161f * 1.4426950408889634f;
    gemm_qkvo<<<dim3(1536), dim3(256), 0, stream>>>(
        v1b, v2b, wcat, bq, bk, bv, bo, Qb, Kb, Vtb, adj, qscale);

    attn_fused<<<dim3(48, 16), dim3(256), 0, stream>>>(Qb, Kb, Vtb, adj, alpha, beta, out);
}